// Round 1
// baseline (1290.812 us; speedup 1.0000x reference)
//
#include <hip/hip_runtime.h>

typedef unsigned int u32;
typedef unsigned short u16;

#define B_ 2048
#define A_ 4096
#define D_ 32768
#define K_ 4096
#define CAP 131072

using f32x4 = __attribute__((ext_vector_type(4))) float;
using bf16x8 = __attribute__((ext_vector_type(8))) short;

typedef const u32 __attribute__((address_space(1)))* gas_ptr;
typedef u32 __attribute__((address_space(3)))* las_ptr;

__device__ __forceinline__ u16 f2bf(float f) {
  u32 u = __float_as_uint(f);
  u32 r = (u + 0x7fffu + ((u >> 16) & 1u)) >> 16;
  return (u16)r;
}

__device__ __forceinline__ void load16(const void* g, void* l) {
  __builtin_amdgcn_global_load_lds((gas_ptr)g, (las_ptr)l, 16, 0, 0);
}

// ---------------- conversions ----------------
__global__ void k_conv_x(const float* __restrict__ x, const float* __restrict__ b_dec,
                         u16* __restrict__ Xb) {
  long t = (long)blockIdx.x * 256 + threadIdx.x;
  long i0 = t * 8;
  int a0 = (int)(i0 & (A_ - 1));
  float4 x0 = *(const float4*)(x + i0);
  float4 x1 = *(const float4*)(x + i0 + 4);
  float4 b0 = *(const float4*)(b_dec + a0);
  float4 b1 = *(const float4*)(b_dec + a0 + 4);
  union { u16 s[8]; uint4 v; } o;
  o.s[0]=f2bf(x0.x-b0.x); o.s[1]=f2bf(x0.y-b0.y); o.s[2]=f2bf(x0.z-b0.z); o.s[3]=f2bf(x0.w-b0.w);
  o.s[4]=f2bf(x1.x-b1.x); o.s[5]=f2bf(x1.y-b1.y); o.s[6]=f2bf(x1.z-b1.z); o.s[7]=f2bf(x1.w-b1.w);
  *(uint4*)(Xb + i0) = o.v;
}

__global__ void k_conv_w(const float* __restrict__ Wf, u16* __restrict__ Wb) {
  long t = (long)blockIdx.x * 256 + threadIdx.x;
  long i0 = t * 8;
  float4 x0 = *(const float4*)(Wf + i0);
  float4 x1 = *(const float4*)(Wf + i0 + 4);
  union { u16 s[8]; uint4 v; } o;
  o.s[0]=f2bf(x0.x); o.s[1]=f2bf(x0.y); o.s[2]=f2bf(x0.z); o.s[3]=f2bf(x0.w);
  o.s[4]=f2bf(x1.x); o.s[5]=f2bf(x1.y); o.s[6]=f2bf(x1.z); o.s[7]=f2bf(x1.w);
  *(uint4*)(Wb + i0) = o.v;
}

// ---------------- bf16 screening GEMM (m97-style 128x128x32, 4 waves) ----------------
__global__ void k_gemm(const u16* __restrict__ Xb, const u16* __restrict__ Wb,
                       const float* __restrict__ b_enc, u16* __restrict__ Z,
                       u32* __restrict__ ghist) {
  __shared__ u16 As[2][128 * 32];
  __shared__ u16 Bs[2][128 * 32];
  __shared__ u32 hist[2048];
  const int tid = threadIdx.x;
  const int lane = tid & 63, wid = tid >> 6;

  // XCD-aware swizzle: 4096 blocks, 8 XCDs -> contiguous 512-block chunks
  int bid = blockIdx.x;
  int virt = (bid & 7) * 512 + (bid >> 3);
  int bm = virt & 15, bn = virt >> 4;     // 16 m-tiles fastest: share W-panel in L2
  const long m0 = (long)bm * 128, n0 = (long)bn * 128;

  for (int i = tid; i < 2048; i += 256) hist[i] = 0;

  const u16* Asrc = Xb + m0 * A_;
  const u16* Bsrc = Wb + n0 * A_;
  const int r = tid >> 2, s = tid & 3;
  const long goff = (long)r * A_ + s * 8;

  auto stage = [&](int buf, int kt) {
    const u16* ga = Asrc + goff + kt * 32;
    const u16* gb = Bsrc + goff + kt * 32;
    u16* la = &As[buf][tid * 8];
    u16* lb = &Bs[buf][tid * 8];
    load16(ga, la);
    load16(ga + (long)64 * A_, la + 64 * 32);
    load16(gb, lb);
    load16(gb + (long)64 * A_, lb + 64 * 32);
  };

  stage(0, 0);
  f32x4 acc[4][4] = {};
  const int wr = wid >> 1, wc = wid & 1;
  const int l15 = lane & 15, lh = lane >> 4;
  const int aoff = (wr * 64 + l15) * 32 + lh * 8;
  const int boff = (wc * 64 + l15) * 32 + lh * 8;
  __syncthreads();

  for (int kt = 0; kt < A_ / 32; ++kt) {
    const int buf = kt & 1;
    if (kt + 1 < A_ / 32) stage(buf ^ 1, kt + 1);
    bf16x8 af[4], bfr[4];
#pragma unroll
    for (int i = 0; i < 4; ++i) {
      af[i]  = *(const bf16x8*)&As[buf][aoff + i * 512];
      bfr[i] = *(const bf16x8*)&Bs[buf][boff + i * 512];
    }
#pragma unroll
    for (int mi = 0; mi < 4; ++mi)
#pragma unroll
      for (int ni = 0; ni < 4; ++ni)
        acc[mi][ni] = __builtin_amdgcn_mfma_f32_16x16x32_bf16(af[mi], bfr[ni], acc[mi][ni], 0, 0, 0);
    __syncthreads();
  }

  // epilogue: +b_enc, relu, bf16 z store, tail histogram over [2,8)
  const long gm0 = m0 + wr * 64 + lh * 4;
  const long gn0 = n0 + wc * 64 + l15;
#pragma unroll
  for (int ni = 0; ni < 4; ++ni) {
    const long col = gn0 + ni * 16;
    const float be = b_enc[col];
#pragma unroll
    for (int mi = 0; mi < 4; ++mi) {
#pragma unroll
      for (int rr = 0; rr < 4; ++rr) {
        const long row = gm0 + mi * 16 + rr;
        float v = acc[mi][ni][rr] + be;
        v = fmaxf(v, 0.f);
        if (v >= 2.0f) {
          u32 bin = (__float_as_uint(v) - 0x40000000u) >> 13;
          if (bin > 2047u) bin = 2047u;
          atomicAdd(&hist[bin], 1u);
        }
        Z[row * D_ + col] = f2bf(v);
      }
    }
  }
  __syncthreads();
  for (int i = tid; i < 2048; i += 256) { u32 c = hist[i]; if (c) atomicAdd(&ghist[i], c); }
}

// ---------------- threshold from histogram ----------------
__global__ void k_tau(const u32* __restrict__ ghist, float* __restrict__ meta_f) {
  if (threadIdx.x) return;
  u32 cum = 0; int b = 2047;
  for (; b >= 0; --b) { cum += ghist[b]; if (cum >= (u32)K_) break; }
  float ta = (b >= 0) ? __uint_as_float(0x40000000u + ((u32)b << 13)) : 2.0f;
  meta_f[0] = ta - 0.1f;   // margin >> bf16-GEMM error bound + bf16 z-store rounding
}

// ---------------- scan z_bf16 for candidates ----------------
__global__ void k_scan(const u16* __restrict__ Z, const float* __restrict__ meta_f,
                       u32* __restrict__ meta_u, u32* __restrict__ cidx) {
  const float tau = meta_f[0];
  const long t = (long)blockIdx.x * 256 + threadIdx.x;
  const long base = t * 16;
  uint4 d0 = *(const uint4*)(Z + base);
  uint4 d1 = *(const uint4*)(Z + base + 8);
  u32 wd[8] = {d0.x, d0.y, d0.z, d0.w, d1.x, d1.y, d1.z, d1.w};
#pragma unroll
  for (int i = 0; i < 8; ++i) {
    float v0 = __uint_as_float((wd[i] & 0xffffu) << 16);
    float v1 = __uint_as_float(wd[i] & 0xffff0000u);
    if (v0 >= tau) { u32 p = atomicAdd(&meta_u[1], 1u); if (p < CAP) cidx[p] = (u32)(base + i * 2); }
    if (v1 >= tau) { u32 p = atomicAdd(&meta_u[1], 1u); if (p < CAP) cidx[p] = (u32)(base + i * 2 + 1); }
  }
}

// ---------------- exact fp32 recompute per candidate (one wave each) ----------------
__global__ void k_recompute(const float* __restrict__ x, const float* __restrict__ W,
                            const float* __restrict__ b_enc, const float* __restrict__ b_dec,
                            const u32* __restrict__ meta_u, const u32* __restrict__ cidx,
                            float* __restrict__ cval) {
  const int lane = threadIdx.x & 63;
  const u32 wglob = blockIdx.x * 4 + (threadIdx.x >> 6);
  u32 n = meta_u[1]; if (n > CAP) n = CAP;
  for (u32 j = wglob; j < n; j += 4096) {
    const u32 idx = cidx[j];
    const int bb = idx >> 15;
    const int dd = idx & (D_ - 1);
    const float4* xp = (const float4*)(x + (long)bb * A_);
    const float4* wp = (const float4*)(W + (long)dd * A_);
    const float4* bp = (const float4*)b_dec;
    float sacc = 0.f;
#pragma unroll
    for (int i = 0; i < 16; ++i) {
      float4 xv = xp[i * 64 + lane], bv = bp[i * 64 + lane], wv = wp[i * 64 + lane];
      sacc += (xv.x - bv.x) * wv.x + (xv.y - bv.y) * wv.y +
              (xv.z - bv.z) * wv.z + (xv.w - bv.w) * wv.w;
    }
#pragma unroll
    for (int o = 32; o > 0; o >>= 1) sacc += __shfl_xor(sacc, o);
    if (lane == 0) cval[j] = fmaxf(sacc + b_enc[dd], 0.f);
  }
}

// ---------------- exact K-th largest via 4-pass radix select ----------------
__global__ void k_radix(const u32* __restrict__ meta_in, const float* __restrict__ cval,
                        u32* __restrict__ meta_u) {
  __shared__ u32 hist[256];
  __shared__ u32 sprefix, scgt, skrem;
  u32 n = meta_in[1]; if (n > CAP) n = CAP;
  if (threadIdx.x == 0) { sprefix = 0; scgt = 0; skrem = K_; }
  __syncthreads();
  for (int pass = 0; pass < 4; ++pass) {
    const int shift = 24 - 8 * pass;
    if (threadIdx.x < 256) hist[threadIdx.x] = 0;
    __syncthreads();
    const u32 pfx = sprefix;
    for (u32 j = threadIdx.x; j < n; j += 1024) {
      const u32 key = __float_as_uint(cval[j]);   // relu'd -> non-negative -> monotone bits
      if (pass == 0 || (key >> (shift + 8)) == pfx)
        atomicAdd(&hist[(key >> shift) & 255u], 1u);
    }
    __syncthreads();
    if (threadIdx.x == 0) {
      u32 cum = 0; int dg = 255;
      const u32 kr = skrem;
      for (; dg > 0; --dg) { if (cum + hist[dg] >= kr) break; cum += hist[dg]; }
      scgt += cum; skrem = kr - cum; sprefix = (pfx << 8) | (u32)dg;
    }
    __syncthreads();
  }
  if (threadIdx.x == 0) { meta_u[2] = sprefix; meta_u[3] = scgt; meta_u[4] = skrem; }
}

// ---------------- emit selected + equal-to-threshold lists ----------------
__global__ void k_emit(const u32* __restrict__ meta_in, const u32* __restrict__ cidx,
                       const float* __restrict__ cval, u32* __restrict__ meta_u,
                       u32* __restrict__ sel_idx, float* __restrict__ sel_val,
                       u32* __restrict__ eq_idx) {
  u32 n = meta_in[1]; if (n > CAP) n = CAP;
  const u32 tkey = meta_in[2];
  for (u32 j = blockIdx.x * 256 + threadIdx.x; j < n; j += gridDim.x * 256) {
    const u32 key = __float_as_uint(cval[j]);
    if (key > tkey) {
      u32 p = atomicAdd(&meta_u[5], 1u);
      sel_idx[p] = cidx[j]; sel_val[p] = cval[j];
    } else if (key == tkey) {
      u32 p = atomicAdd(&meta_u[6], 1u);
      if (p < 4096u) eq_idx[p] = cidx[j];
    }
  }
}

// ---------------- tie-break: smallest flat indices first (lax.top_k semantics) ----------------
__global__ void k_final(const u32* __restrict__ meta_u, u32* __restrict__ sel_idx,
                        float* __restrict__ sel_val, const u32* __restrict__ eq_idx) {
  if (threadIdx.x) return;
  const u32 cgt = meta_u[3], need = meta_u[4];
  u32 neq = meta_u[6]; if (neq > 4096u) neq = 4096u;
  const float tv = __uint_as_float(meta_u[2]);
  u32 last = 0; bool first = true;
  for (u32 rr = 0; rr < need; ++rr) {
    u32 best = 0xFFFFFFFFu;
    for (u32 i = 0; i < neq; ++i) {
      const u32 v = eq_idx[i];
      if ((first || v > last) && v < best) best = v;
    }
    sel_idx[cgt + rr] = best; sel_val[cgt + rr] = tv;
    last = best; first = false;
  }
}

// ---------------- decode ----------------
__global__ void k_init_out(float* __restrict__ out, const float* __restrict__ b_dec) {
  const long t = (long)blockIdx.x * 256 + threadIdx.x;
  const int a = ((int)t & 1023) * 4;
  *(float4*)(out + t * 4) = *(const float4*)(b_dec + a);
}

__global__ void k_scatter(const u32* __restrict__ sel_idx, const float* __restrict__ sel_val,
                          const float* __restrict__ Wd, float* __restrict__ out) {
  const u32 idx = sel_idx[blockIdx.x];
  const float act = sel_val[blockIdx.x];
  const int bb = idx >> 15, dd = idx & (D_ - 1);
  const float4* wp = (const float4*)(Wd + (long)dd * A_);
  float* op = out + (long)bb * A_;
#pragma unroll
  for (int c = 0; c < 4; ++c) {
    const int e = threadIdx.x + c * 256;
    const float4 wv = wp[e];
    atomicAdd(op + e * 4 + 0, act * wv.x);
    atomicAdd(op + e * 4 + 1, act * wv.y);
    atomicAdd(op + e * 4 + 2, act * wv.z);
    atomicAdd(op + e * 4 + 3, act * wv.w);
  }
}

extern "C" void kernel_launch(void* const* d_in, const int* in_sizes, int n_in,
                              void* d_out, int out_size, void* d_ws, size_t ws_size,
                              hipStream_t stream) {
  const float* x     = (const float*)d_in[0];
  const float* W_enc = (const float*)d_in[1];
  const float* b_enc = (const float*)d_in[2];
  const float* W_dec = (const float*)d_in[3];
  const float* b_dec = (const float*)d_in[4];
  float* out = (float*)d_out;
  char* w = (char*)d_ws;

  const long off_Xb   = 0L;
  const long off_Wb   = 16777216L;                 // 16 MiB
  const long off_Z    = off_Wb + 268435456L;       // +256 MiB -> 285,212,672
  const long off_hist = off_Z + 134217728L;        // +128 MiB -> 419,430,400
  const long off_meta = off_hist + 8192L;          // 419,438,592
  const long off_cidx = off_meta + 256L;           // 419,438,848
  const long off_cval = off_cidx + 524288L;        // 419,963,136
  const long off_sidx = off_cval + 524288L;        // 420,487,424
  const long off_sval = off_sidx + 16384L;
  const long off_eq   = off_sval + 16384L;
  const long need_ws  = off_eq + 16384L;           // ~401 MiB
  if ((long)ws_size < need_ws) return;             // cannot run safely

  u16* Xb      = (u16*)(w + off_Xb);
  u16* Wb      = (u16*)(w + off_Wb);
  u16* Z       = (u16*)(w + off_Z);
  u32* ghist   = (u32*)(w + off_hist);
  float* meta_f= (float*)(w + off_meta);
  u32* meta_u  = (u32*)(w + off_meta);
  u32* cidx    = (u32*)(w + off_cidx);
  float* cval  = (float*)(w + off_cval);
  u32* sel_idx = (u32*)(w + off_sidx);
  float* sel_val = (float*)(w + off_sval);
  u32* eq_idx  = (u32*)(w + off_eq);

  // zero histogram + meta counters every call (deterministic)
  hipMemsetAsync(w + off_hist, 0, 8192 + 256, stream);

  k_conv_x<<<4096, 256, 0, stream>>>(x, b_dec, Xb);
  k_conv_w<<<65536, 256, 0, stream>>>(W_enc, Wb);
  k_init_out<<<8192, 256, 0, stream>>>(out, b_dec);
  k_gemm<<<4096, 256, 0, stream>>>(Xb, Wb, b_enc, Z, ghist);
  k_tau<<<1, 64, 0, stream>>>(ghist, meta_f);
  k_scan<<<16384, 256, 0, stream>>>(Z, meta_f, meta_u, cidx);
  k_recompute<<<1024, 256, 0, stream>>>(x, W_enc, b_enc, b_dec, meta_u, cidx, cval);
  k_radix<<<1, 1024, 0, stream>>>(meta_u, cval, meta_u);
  k_emit<<<256, 256, 0, stream>>>(meta_u, cidx, cval, meta_u, sel_idx, sel_val, eq_idx);
  k_final<<<1, 64, 0, stream>>>(meta_u, sel_idx, sel_val, eq_idx);
  k_scatter<<<4096, 256, 0, stream>>>(sel_idx, sel_val, W_dec, out);
}

// Round 2
// 1181.606 us; speedup vs baseline: 1.0924x; 1.0924x over previous
//
#include <hip/hip_runtime.h>

typedef unsigned int u32;
typedef unsigned short u16;

#define B_ 2048
#define A_ 4096
#define D_ 32768
#define K_ 4096
#define CAP0 4194304   // raw candidates (v >= 2.0), expect ~1.5M
#define CAP  131072    // filtered candidates (v >= tau), expect ~6K
#define STASH 512

using f32x4 = __attribute__((ext_vector_type(4))) float;
using bf16x8 = __attribute__((ext_vector_type(8))) short;

typedef const u32 __attribute__((address_space(1)))* gas_ptr;
typedef u32 __attribute__((address_space(3)))* las_ptr;

__device__ __forceinline__ u16 f2bf(float f) {
  u32 u = __float_as_uint(f);
  u32 r = (u + 0x7fffu + ((u >> 16) & 1u)) >> 16;
  return (u16)r;
}

__device__ __forceinline__ void load16(const void* g, void* l) {
  __builtin_amdgcn_global_load_lds((gas_ptr)g, (las_ptr)l, 16, 0, 0);
}

// ---------------- conversions ----------------
__global__ void k_conv_x(const float* __restrict__ x, const float* __restrict__ b_dec,
                         u16* __restrict__ Xb) {
  long t = (long)blockIdx.x * 256 + threadIdx.x;
  long i0 = t * 8;
  int a0 = (int)(i0 & (A_ - 1));
  float4 x0 = *(const float4*)(x + i0);
  float4 x1 = *(const float4*)(x + i0 + 4);
  float4 b0 = *(const float4*)(b_dec + a0);
  float4 b1 = *(const float4*)(b_dec + a0 + 4);
  union { u16 s[8]; uint4 v; } o;
  o.s[0]=f2bf(x0.x-b0.x); o.s[1]=f2bf(x0.y-b0.y); o.s[2]=f2bf(x0.z-b0.z); o.s[3]=f2bf(x0.w-b0.w);
  o.s[4]=f2bf(x1.x-b1.x); o.s[5]=f2bf(x1.y-b1.y); o.s[6]=f2bf(x1.z-b1.z); o.s[7]=f2bf(x1.w-b1.w);
  *(uint4*)(Xb + i0) = o.v;
}

__global__ void k_conv_w(const float* __restrict__ Wf, u16* __restrict__ Wb) {
  long t = (long)blockIdx.x * 256 + threadIdx.x;
  long i0 = t * 8;
  float4 x0 = *(const float4*)(Wf + i0);
  float4 x1 = *(const float4*)(Wf + i0 + 4);
  union { u16 s[8]; uint4 v; } o;
  o.s[0]=f2bf(x0.x); o.s[1]=f2bf(x0.y); o.s[2]=f2bf(x0.z); o.s[3]=f2bf(x0.w);
  o.s[4]=f2bf(x1.x); o.s[5]=f2bf(x1.y); o.s[6]=f2bf(x1.z); o.s[7]=f2bf(x1.w);
  *(uint4*)(Wb + i0) = o.v;
}

// ---------------- bf16 screening GEMM (128x128x32, 4 waves, T2 swizzle) ----------------
__global__ void k_gemm(const u16* __restrict__ Xb, const u16* __restrict__ Wb,
                       const float* __restrict__ b_enc,
                       u32* meta_u, u32* __restrict__ c0i, float* __restrict__ c0v) {
  __shared__ u16 As[2][128 * 32];
  __shared__ u16 Bs[2][128 * 32];
  __shared__ u32 s_sidx[STASH];
  __shared__ float s_sval[STASH];
  __shared__ u32 s_cnt, s_base;
  const int tid = threadIdx.x;
  const int lane = tid & 63, wid = tid >> 6;

  // XCD-aware swizzle: 4096 blocks, 8 XCDs -> contiguous 512-block chunks
  int bid = blockIdx.x;
  int virt = (bid & 7) * 512 + (bid >> 3);
  int bm = virt & 15, bn = virt >> 4;     // 16 m-tiles fastest: share W-panel in L2
  const long m0 = (long)bm * 128, n0 = (long)bn * 128;

  if (tid == 0) s_cnt = 0;

  const u16* Asrc = Xb + m0 * A_;
  const u16* Bsrc = Wb + n0 * A_;
  const int r = tid >> 2, s = tid & 3;
  const int sx = s ^ ((r >> 1) & 3);                 // inverse-swizzled global slot
  const long goff = (long)r * A_ + sx * 8;           // (r+64 has same (r>>1)&3 -> same sx)

  auto stage = [&](int buf, int kt) {
    const u16* ga = Asrc + goff + kt * 32;
    const u16* gb = Bsrc + goff + kt * 32;
    u16* la = &As[buf][tid * 8];
    u16* lb = &Bs[buf][tid * 8];
    load16(ga, la);
    load16(ga + (long)64 * A_, la + 64 * 32);
    load16(gb, lb);
    load16(gb + (long)64 * A_, lb + 64 * 32);
  };

  stage(0, 0);
  f32x4 acc[4][4] = {};
  const int wr = wid >> 1, wc = wid & 1;
  const int l15 = lane & 15, lh = lane >> 4;
  const int swz = (l15 >> 1) & 3;                    // (row>>1)&3, invariant in wr/mi
  const int aoff = (wr * 64 + l15) * 32 + (lh ^ swz) * 8;
  const int boff = (wc * 64 + l15) * 32 + (lh ^ swz) * 8;
  __syncthreads();

  for (int kt = 0; kt < A_ / 32; ++kt) {
    const int buf = kt & 1;
    if (kt + 1 < A_ / 32) stage(buf ^ 1, kt + 1);
    bf16x8 af[4], bfr[4];
#pragma unroll
    for (int i = 0; i < 4; ++i) {
      af[i]  = *(const bf16x8*)&As[buf][aoff + i * 512];
      bfr[i] = *(const bf16x8*)&Bs[buf][boff + i * 512];
    }
#pragma unroll
    for (int mi = 0; mi < 4; ++mi)
#pragma unroll
      for (int ni = 0; ni < 4; ++ni)
        acc[mi][ni] = __builtin_amdgcn_mfma_f32_16x16x32_bf16(af[mi], bfr[ni], acc[mi][ni], 0, 0, 0);
    __syncthreads();
  }

  // epilogue: +b_enc, relu, emit candidates (v>=2.0) via LDS stash
  const long gm0 = m0 + wr * 64 + lh * 4;
  const long gn0 = n0 + wc * 64 + l15;
#pragma unroll
  for (int ni = 0; ni < 4; ++ni) {
    const long col = gn0 + ni * 16;
    const float be = b_enc[col];
#pragma unroll
    for (int mi = 0; mi < 4; ++mi) {
#pragma unroll
      for (int rr = 0; rr < 4; ++rr) {
        const long row = gm0 + mi * 16 + rr;
        float v = fmaxf(acc[mi][ni][rr] + be, 0.f);
        if (v >= 2.0f) {
          u32 flat = (u32)(row * D_ + col);
          u32 p = atomicAdd(&s_cnt, 1u);
          if (p < STASH) { s_sidx[p] = flat; s_sval[p] = v; }
          else { u32 g = atomicAdd(&meta_u[1], 1u); if (g < CAP0) { c0i[g] = flat; c0v[g] = v; } }
        }
      }
    }
  }
  __syncthreads();
  if (tid == 0) s_base = atomicAdd(&meta_u[1], s_cnt < (u32)STASH ? s_cnt : (u32)STASH);
  __syncthreads();
  const u32 c = s_cnt < (u32)STASH ? s_cnt : (u32)STASH;
  for (u32 i = tid; i < c; i += 256) {
    u32 g = s_base + i;
    if (g < CAP0) { c0i[g] = s_sidx[i]; c0v[g] = s_sval[i]; }
  }
}

// ---------------- histogram over raw candidates ----------------
__global__ void k_hist(const float* __restrict__ c0v, const u32* meta_u,
                       u32* __restrict__ ghist) {
  __shared__ u32 h[2048];
  for (int i = threadIdx.x; i < 2048; i += 256) h[i] = 0;
  __syncthreads();
  u32 n = meta_u[1]; if (n > CAP0) n = CAP0;
  for (u32 j = blockIdx.x * 256 + threadIdx.x; j < n; j += gridDim.x * 256) {
    u32 bin = (__float_as_uint(c0v[j]) - 0x40000000u) >> 13;   // v>=2 guaranteed
    if (bin > 2047u) bin = 2047u;
    atomicAdd(&h[bin], 1u);
  }
  __syncthreads();
  for (int i = threadIdx.x; i < 2048; i += 256) { u32 cc = h[i]; if (cc) atomicAdd(&ghist[i], cc); }
}

// ---------------- threshold from histogram ----------------
__global__ void k_tau(const u32* __restrict__ ghist, float* meta_f) {
  if (threadIdx.x) return;
  u32 cum = 0; int b = 2047;
  for (; b >= 0; --b) { cum += ghist[b]; if (cum >= (u32)K_) break; }
  float ta = (b >= 0) ? __uint_as_float(0x40000000u + ((u32)b << 13)) : 2.0f;
  meta_f[0] = ta - 0.1f;   // margin >> bf16-GEMM accumulation error bound
}

// ---------------- filter raw candidates by tau ----------------
__global__ void k_filter(const u32* __restrict__ c0i, const float* __restrict__ c0v,
                         const float* meta_f, u32* meta_u, u32* __restrict__ cidx2) {
  const float tau = meta_f[0];
  u32 n = meta_u[1]; if (n > CAP0) n = CAP0;
  for (u32 j = blockIdx.x * 256 + threadIdx.x; j < n; j += gridDim.x * 256) {
    if (c0v[j] >= tau) {
      u32 p = atomicAdd(&meta_u[7], 1u);
      if (p < CAP) cidx2[p] = c0i[j];
    }
  }
}

// ---------------- exact fp32 recompute per candidate (one wave each) ----------------
__global__ void k_recompute(const float* __restrict__ x, const float* __restrict__ W,
                            const float* __restrict__ b_enc, const float* __restrict__ b_dec,
                            const u32* meta_u, const u32* __restrict__ cidx,
                            float* __restrict__ cval) {
  const int lane = threadIdx.x & 63;
  const u32 wglob = blockIdx.x * 4 + (threadIdx.x >> 6);
  u32 n = meta_u[7]; if (n > CAP) n = CAP;
  for (u32 j = wglob; j < n; j += 4096) {
    const u32 idx = cidx[j];
    const int bb = idx >> 15;
    const int dd = idx & (D_ - 1);
    const float4* xp = (const float4*)(x + (long)bb * A_);
    const float4* wp = (const float4*)(W + (long)dd * A_);
    const float4* bp = (const float4*)b_dec;
    float sacc = 0.f;
#pragma unroll
    for (int i = 0; i < 16; ++i) {
      float4 xv = xp[i * 64 + lane], bv = bp[i * 64 + lane], wv = wp[i * 64 + lane];
      sacc += (xv.x - bv.x) * wv.x + (xv.y - bv.y) * wv.y +
              (xv.z - bv.z) * wv.z + (xv.w - bv.w) * wv.w;
    }
#pragma unroll
    for (int o = 32; o > 0; o >>= 1) sacc += __shfl_xor(sacc, o);
    if (lane == 0) cval[j] = fmaxf(sacc + b_enc[dd], 0.f);
  }
}

// ---------------- exact K-th largest via 4-pass radix select ----------------
__global__ void k_radix(const u32* meta_in, const float* __restrict__ cval,
                        u32* meta_u) {
  __shared__ u32 hist[256];
  __shared__ u32 sprefix, scgt, skrem;
  u32 n = meta_in[7]; if (n > CAP) n = CAP;
  if (threadIdx.x == 0) { sprefix = 0; scgt = 0; skrem = K_; }
  __syncthreads();
  for (int pass = 0; pass < 4; ++pass) {
    const int shift = 24 - 8 * pass;
    if (threadIdx.x < 256) hist[threadIdx.x] = 0;
    __syncthreads();
    const u32 pfx = sprefix;
    for (u32 j = threadIdx.x; j < n; j += 1024) {
      const u32 key = __float_as_uint(cval[j]);   // relu'd -> non-negative -> monotone bits
      if (pass == 0 || (key >> (shift + 8)) == pfx)
        atomicAdd(&hist[(key >> shift) & 255u], 1u);
    }
    __syncthreads();
    if (threadIdx.x == 0) {
      u32 cum = 0; int dg = 255;
      const u32 kr = skrem;
      for (; dg > 0; --dg) { if (cum + hist[dg] >= kr) break; cum += hist[dg]; }
      scgt += cum; skrem = kr - cum; sprefix = (pfx << 8) | (u32)dg;
    }
    __syncthreads();
  }
  if (threadIdx.x == 0) { meta_u[2] = sprefix; meta_u[3] = scgt; meta_u[4] = skrem; }
}

// ---------------- emit selected + equal-to-threshold lists ----------------
__global__ void k_emit(const u32* meta_in, const u32* __restrict__ cidx,
                       const float* __restrict__ cval, u32* meta_u,
                       u32* __restrict__ sel_idx, float* __restrict__ sel_val,
                       u32* __restrict__ eq_idx) {
  u32 n = meta_in[7]; if (n > CAP) n = CAP;
  const u32 tkey = meta_in[2];
  for (u32 j = blockIdx.x * 256 + threadIdx.x; j < n; j += gridDim.x * 256) {
    const u32 key = __float_as_uint(cval[j]);
    if (key > tkey) {
      u32 p = atomicAdd(&meta_u[5], 1u);
      sel_idx[p] = cidx[j]; sel_val[p] = cval[j];
    } else if (key == tkey) {
      u32 p = atomicAdd(&meta_u[6], 1u);
      if (p < 4096u) eq_idx[p] = cidx[j];
    }
  }
}

// ---------------- tie-break: smallest flat indices first (lax.top_k semantics) ----------------
__global__ void k_final(const u32* meta_u, u32* __restrict__ sel_idx,
                        float* __restrict__ sel_val, const u32* __restrict__ eq_idx) {
  if (threadIdx.x) return;
  const u32 cgt = meta_u[3], need = meta_u[4];
  u32 neq = meta_u[6]; if (neq > 4096u) neq = 4096u;
  const float tv = __uint_as_float(meta_u[2]);
  u32 last = 0; bool first = true;
  for (u32 rr = 0; rr < need; ++rr) {
    u32 best = 0xFFFFFFFFu;
    for (u32 i = 0; i < neq; ++i) {
      const u32 v = eq_idx[i];
      if ((first || v > last) && v < best) best = v;
    }
    sel_idx[cgt + rr] = best; sel_val[cgt + rr] = tv;
    last = best; first = false;
  }
}

// ---------------- decode ----------------
__global__ void k_init_out(float* __restrict__ out, const float* __restrict__ b_dec) {
  const long t = (long)blockIdx.x * 256 + threadIdx.x;
  const int a = ((int)t & 1023) * 4;
  *(float4*)(out + t * 4) = *(const float4*)(b_dec + a);
}

__global__ void k_scatter(const u32* __restrict__ sel_idx, const float* __restrict__ sel_val,
                          const float* __restrict__ Wd, float* __restrict__ out) {
  const u32 idx = sel_idx[blockIdx.x];
  const float act = sel_val[blockIdx.x];
  const int bb = idx >> 15, dd = idx & (D_ - 1);
  const float4* wp = (const float4*)(Wd + (long)dd * A_);
  float* op = out + (long)bb * A_;
#pragma unroll
  for (int c = 0; c < 4; ++c) {
    const int e = threadIdx.x + c * 256;
    const float4 wv = wp[e];
    atomicAdd(op + e * 4 + 0, act * wv.x);
    atomicAdd(op + e * 4 + 1, act * wv.y);
    atomicAdd(op + e * 4 + 2, act * wv.z);
    atomicAdd(op + e * 4 + 3, act * wv.w);
  }
}

extern "C" void kernel_launch(void* const* d_in, const int* in_sizes, int n_in,
                              void* d_out, int out_size, void* d_ws, size_t ws_size,
                              hipStream_t stream) {
  const float* x     = (const float*)d_in[0];
  const float* W_enc = (const float*)d_in[1];
  const float* b_enc = (const float*)d_in[2];
  const float* W_dec = (const float*)d_in[3];
  const float* b_dec = (const float*)d_in[4];
  float* out = (float*)d_out;
  char* w = (char*)d_ws;

  const long off_Xb   = 0L;
  const long off_Wb   = 16777216L;                  // 16 MiB
  const long off_c0i  = off_Wb + 268435456L;        // 285,212,672
  const long off_c0v  = off_c0i + 16777216L;        // 301,989,888
  const long off_hist = off_c0v + 16777216L;        // 318,767,104
  const long off_meta = off_hist + 8192L;
  const long off_ci2  = off_meta + 256L;
  const long off_cv2  = off_ci2 + 524288L;
  const long off_sidx = off_cv2 + 524288L;
  const long off_sval = off_sidx + 16384L;
  const long off_eq   = off_sval + 16384L;
  const long need_ws  = off_eq + 16384L;            // ~305 MiB
  if ((long)ws_size < need_ws) return;              // cannot run safely

  u16* Xb      = (u16*)(w + off_Xb);
  u16* Wb      = (u16*)(w + off_Wb);
  u32* c0i     = (u32*)(w + off_c0i);
  float* c0v   = (float*)(w + off_c0v);
  u32* ghist   = (u32*)(w + off_hist);
  float* meta_f= (float*)(w + off_meta);
  u32* meta_u  = (u32*)(w + off_meta);
  u32* cidx2   = (u32*)(w + off_ci2);
  float* cval2 = (float*)(w + off_cv2);
  u32* sel_idx = (u32*)(w + off_sidx);
  float* sel_val = (float*)(w + off_sval);
  u32* eq_idx  = (u32*)(w + off_eq);

  // zero histogram + meta counters every call (deterministic)
  hipMemsetAsync(w + off_hist, 0, 8192 + 256, stream);

  k_conv_x<<<4096, 256, 0, stream>>>(x, b_dec, Xb);
  k_conv_w<<<65536, 256, 0, stream>>>(W_enc, Wb);
  k_init_out<<<8192, 256, 0, stream>>>(out, b_dec);
  k_gemm<<<4096, 256, 0, stream>>>(Xb, Wb, b_enc, meta_u, c0i, c0v);
  k_hist<<<512, 256, 0, stream>>>(c0v, meta_u, ghist);
  k_tau<<<1, 64, 0, stream>>>(ghist, meta_f);
  k_filter<<<2048, 256, 0, stream>>>(c0i, c0v, meta_f, meta_u, cidx2);
  k_recompute<<<1024, 256, 0, stream>>>(x, W_enc, b_enc, b_dec, meta_u, cidx2, cval2);
  k_radix<<<1, 1024, 0, stream>>>(meta_u, cval2, meta_u);
  k_emit<<<256, 256, 0, stream>>>(meta_u, cidx2, cval2, meta_u, sel_idx, sel_val, eq_idx);
  k_final<<<1, 64, 0, stream>>>(meta_u, sel_idx, sel_val, eq_idx);
  k_scatter<<<K_, 256, 0, stream>>>(sel_idx, sel_val, W_dec, out);
}